// Round 1
// baseline (192.344 us; speedup 1.0000x reference)
//
#include <hip/hip_runtime.h>

#define HH 128
#define WW 128
#define CC 96
#define KK 7

// Streaming-accumulator morphological dilation (7x7, zero-pad, ReLU folded).
// Block: 256 threads = 32 col-groups x 8 row-groups; covers one (b,c) plane
// half (64 rows x 128 cols). Thread: 4 cols (tc0..tc0+3), 8 output rows
// (row0..row0+7). Instead of a 7x12 ring window (~70 live floats), stream
// input rows top-down: each row is loaded into a transient 12-float register
// strip, immediately max-plus-reduced into the (<=7) pending output-row
// accumulators it contributes to, then dead. acc[8][4] = 32 regs; weight row
// selection i = s - yl folds at compile time under full unroll.

__device__ __forceinline__ void load_row(float* d, const float* __restrict__ xp,
                                         int r, int tc0, bool lok, bool rok) {
  if ((unsigned)r < (unsigned)HH) {
    const float* p = xp + r * WW + tc0 - 4;
    float4 a, b, c;
    if (lok) a = *(const float4*)(p);
    else     a = make_float4(0.f, 0.f, 0.f, 0.f);
    b = *(const float4*)(p + 4);
    if (rok) c = *(const float4*)(p + 8);
    else     c = make_float4(0.f, 0.f, 0.f, 0.f);
    d[0] = a.x; d[1] = a.y; d[2] = a.z; d[3] = a.w;
    d[4] = b.x; d[5] = b.y; d[6] = b.z; d[7] = b.w;
    d[8] = c.x; d[9] = c.y; d[10] = c.z; d[11] = c.w;
  } else {
#pragma unroll
    for (int i = 0; i < 12; ++i) d[i] = 0.f;
  }
}

__global__ __launch_bounds__(256) void morph_kernel(
    const float* __restrict__ x, const float* __restrict__ weight,
    float* __restrict__ out) {
  const int t = threadIdx.x;
  const int cg = t & 31;   // col group 0..31
  const int rg = t >> 5;   // row group 0..7
  const int half = blockIdx.x & 1;
  const int plane = blockIdx.x >> 1;  // b*CC + c
  const int c = plane % CC;

  const float* __restrict__ xp = x + (size_t)plane * (HH * WW);
  float* __restrict__ op = out + (size_t)plane * (HH * WW);
  const float* __restrict__ Wc = weight + c * (KK * KK);

  // Preload 49 channel weights; force into SGPRs (block-uniform).
  float wv[KK * KK];
#pragma unroll
  for (int k = 0; k < KK * KK; ++k)
    wv[k] = __int_as_float(__builtin_amdgcn_readfirstlane(__float_as_int(Wc[k])));

  const int tc0 = cg << 2;              // first out col of this thread
  const int row0 = half * 64 + rg * 8;  // first out row of this thread
  const bool lok = (tc0 >= 4);
  const bool rok = (tc0 <= WW - 8);

  // Pending output accumulators. ReLU folded in: start at 0 (= max(0, .)).
  float acc[8][4];
#pragma unroll
  for (int y = 0; y < 8; ++y)
#pragma unroll
    for (int q = 0; q < 4; ++q) acc[y][q] = 0.f;

  // Stream input rows row0-3 .. row0+10 (14 rows for 8 output rows).
#pragma unroll
  for (int s = 0; s < 14; ++s) {
    float d[12];  // cols [tc0-4, tc0+8); used: d[1..10]
    load_row(d, xp, row0 - 3 + s, tc0, lok, rok);

#pragma unroll
    for (int yl = 0; yl < 8; ++yl) {
      const int i = s - yl;            // weight row; folds at compile time
      if (i < 0 || i >= KK) continue;  // static guard (full unroll)
      const float w0 = wv[i * 7 + 0], w1 = wv[i * 7 + 1], w2 = wv[i * 7 + 2],
                  w3 = wv[i * 7 + 3], w4 = wv[i * 7 + 4], w5 = wv[i * 7 + 5],
                  w6 = wv[i * 7 + 6];
#pragma unroll
      for (int q = 0; q < 4; ++q) {
        const float t0 = d[q + 1] + w0;
        const float t1 = d[q + 2] + w1;
        const float t2 = d[q + 3] + w2;
        const float t3 = d[q + 4] + w3;
        const float t4 = d[q + 5] + w4;
        const float t5 = d[q + 6] + w5;
        const float t6 = d[q + 7] + w6;
        float m = acc[yl][q];
        // fmax chains select to v_max3_f32: 4 max instrs for 7 taps.
        m = fmaxf(fmaxf(m, t0), t1);
        m = fmaxf(fmaxf(m, t2), t3);
        m = fmaxf(fmaxf(m, t4), t5);
        m = fmaxf(m, t6);
        acc[yl][q] = m;
      }
    }

    // Output row (row0 + s - 6) got its last contribution this iteration.
    if (s >= 6) {
      const int yl = s - 6;
      float4 o = make_float4(acc[yl][0], acc[yl][1], acc[yl][2], acc[yl][3]);
      *(float4*)(op + (size_t)(row0 + yl) * WW + tc0) = o;
    }
  }
}

extern "C" void kernel_launch(void* const* d_in, const int* in_sizes, int n_in,
                              void* d_out, int out_size, void* d_ws, size_t ws_size,
                              hipStream_t stream) {
  const float* x = (const float*)d_in[0];
  const float* w = (const float*)d_in[1];
  float* out = (float*)d_out;
  // 16 batches * 96 channels * 2 half-planes
  const int nblocks = 16 * CC * 2;
  morph_kernel<<<nblocks, 256, 0, stream>>>(x, w, out);
}